// Round 8
// baseline (18105.283 us; speedup 1.0000x reference)
//
#include <hip/hip_runtime.h>
#include <hip/hip_bf16.h>

#define M_DIM 16384
#define N_DIM 8192
#define K_DIM 4096
#define NT (K_DIM / 64)  // 64 K-tiles, 32 groups of 2

typedef __attribute__((ext_vector_type(4))) float f32x4;
typedef __attribute__((ext_vector_type(8))) __bf16 bf16x8;
typedef __attribute__((ext_vector_type(4))) unsigned short u16x4;

static __device__ __forceinline__ unsigned short f2bf(float f) {
  __bf16 h = (__bf16)f;
  return __builtin_bit_cast(unsigned short, h);
}

static __device__ __forceinline__ void gl_lds16(const unsigned short* g, unsigned short* l) {
  __builtin_amdgcn_global_load_lds(
      (const __attribute__((address_space(1))) unsigned int*)g,
      (__attribute__((address_space(3))) unsigned int*)l, 16, 0, 0);
}

// ---- prep: A [M][K] f32 -> bf16 (same layout) ----
__global__ void k_convert_a(const float* __restrict__ a, unsigned short* __restrict__ o) {
  const size_t n8 = (size_t)M_DIM * K_DIM / 8;
  for (size_t i = (size_t)blockIdx.x * blockDim.x + threadIdx.x; i < n8;
       i += (size_t)gridDim.x * blockDim.x) {
    const f32x4* p = (const f32x4*)(a + i * 8);
    f32x4 v0 = p[0];
    f32x4 v1 = p[1];
    u16x4 r0, r1;
#pragma unroll
    for (int j = 0; j < 4; ++j) { r0[j] = f2bf(v0[j]); r1[j] = f2bf(v1[j]); }
    *(u16x4*)(o + i * 8) = r0;
    *(u16x4*)(o + i * 8 + 4) = r1;
  }
}

// ---- prep: W [K][N] f32 -> Wt [N][K] bf16 (transpose + convert) ----
__global__ void k_convert_w_t(const float* __restrict__ w, unsigned short* __restrict__ wt) {
  __shared__ float tile[64][65];
  const int bk = blockIdx.y * 64;
  const int bn = blockIdx.x * 64;
  const int t = threadIdx.x;  // 256
  const int c4 = (t & 15) * 4;
  const int r = t >> 4;
#pragma unroll
  for (int p = 0; p < 4; ++p) {
    const int row = r + p * 16;
    f32x4 v = *(const f32x4*)&w[(size_t)(bk + row) * N_DIM + bn + c4];
    tile[row][c4 + 0] = v[0];
    tile[row][c4 + 1] = v[1];
    tile[row][c4 + 2] = v[2];
    tile[row][c4 + 3] = v[3];
  }
  __syncthreads();
#pragma unroll
  for (int p = 0; p < 4; ++p) {
    const int c = r + p * 16;
    u16x4 o;
#pragma unroll
    for (int j = 0; j < 4; ++j) o[j] = f2bf(tile[c4 + j][c]);
    *(u16x4*)&wt[(size_t)(bn + c) * K_DIM + bk + c4] = o;
  }
}

// ---- main GEMM: 256x256, BK=64, A in 64KB LDS (2 blocks/CU), B global->reg ----
// LDS 64KB = 2 tile-bufs x {Ak0,Ak1} x 16KB (256 rows x 32 k), A-ONLY.
// B: per-wave 64-col slice loaded straight into MFMA operand regs from
// Wt[N][K] (lane=col, 16B contiguous k) -- no LDS round-trip (no intra-block
// B reuse exists). Double reg set bU/bV, prefetched 1 full tile ahead.
// Per tile: 4 phases (kh0 mL / kh0 mH / kh1 mL / kh1 mH), 4 ds_reads + 16
// MFMA each. Stage slots: P0: Ak1(t+1) [+B(t+1) loads], P2: Ak0(t+2).
// vmcnt(2) at each P3 (leftover invariant = Ak0(t+2)); prologue VMC(0);
// t=62 VMC(0). WAR: each stage >=1 barrier after victim reads published.
// A swizzle: r5's verified 0-conflict form (16-row, granule ^= (fr>>1)&3).
__global__ __launch_bounds__(512, 4) void k_gemm_8ph(
    const unsigned short* __restrict__ A, const unsigned short* __restrict__ Bt,
    const float* __restrict__ bias, float* __restrict__ C) {
  __shared__ __align__(16) unsigned short S[32768];  // 64 KB, A only

  const int tid = threadIdx.x;
  const int lane = tid & 63;
  const int wave = tid >> 6;  // 0..7
  const int wm = wave >> 2;   // 0..1 -> 128-row half
  const int wn = wave & 3;    // 0..3 -> 64-col block
  const int fr = lane & 15;
  const int hi = lane >> 4;   // 0..3

  // T1: XCD-aware bijective swizzle (2048 blocks, %8==0)
  const int bid = blockIdx.x;
  const int swz = (bid & 7) * 256 + (bid >> 3);
  const int local = swz & 255;
  const int tm = local & 63;
  const int tn = (swz >> 8) * 4 + (local >> 6);
  const int brow = tm * 256;
  const int bcol = tn * 256;

  // A staging source: row = tid>>2 (+128 for 2nd gl_lds), dest granule tid&3,
  // source granule = dest ^ ((row>>1)&3) = dest ^ ((tid>>3)&3).
  const int srow2 = tid >> 2;
  const int sgel = ((tid & 3) ^ ((tid >> 3) & 3)) * 8;
  const unsigned short* aS = A + (size_t)(brow + srow2) * K_DIM + sgel;

  // stage A k-half region of tile tt -> region((tt&1), kh), LINEAR dest
#define STG_A(kh, tt)                                                 \
  do {                                                                \
    unsigned short* d_ = S + ((tt)&1) * 16384 + (kh)*8192 + tid * 8;  \
    const unsigned short* g_ = aS + (size_t)(tt)*64 + (kh)*32;        \
    gl_lds16(g_, d_);                                                 \
    gl_lds16(g_ + (size_t)128 * K_DIM, d_ + 4096);                    \
  } while (0)

  // A frag-read swizzled granule (r5-verified): phys = hi ^ ((fr>>1)&3)
  const int swk = ((hi ^ ((fr >> 1) & 3)) * 8);
  const unsigned short* SA = S + (wm * 128 + fr) * 32 + swk;

#define RD_A(dst, X, kh, mb)                                                      \
  _Pragma("unroll") for (int m_ = 0; m_ < 4; ++m_)                                \
      dst[m_] = *(const bf16x8*)(SA + (X)*16384 + (kh)*8192 + ((mb) + m_ * 16) * 32);

  // B direct-load pointers: lane (fr,hi) covers col = bcol+wn*64+n*16+fr,
  // k-granule hi within each 32-k half. 8 loads per tile (4n x 2kh).
  const unsigned short* bG0 = Bt + (size_t)(bcol + wn * 64 + fr) * K_DIM + hi * 8;
  const unsigned short* bGn[4] = {bG0, bG0 + (size_t)16 * K_DIM,
                                  bG0 + (size_t)32 * K_DIM, bG0 + (size_t)48 * K_DIM};
#define LOADB(d0, d1, tt)                                             \
  _Pragma("unroll") for (int n_ = 0; n_ < 4; ++n_) {                  \
    d0[n_] = *(const bf16x8*)(bGn[n_] + (size_t)(tt)*64);             \
    d1[n_] = *(const bf16x8*)(bGn[n_] + (size_t)(tt)*64 + 32);        \
  }

  f32x4 acc[8][4] = {};

#define BAR __builtin_amdgcn_s_barrier()
#define LGKM0 asm volatile("s_waitcnt lgkmcnt(0)" ::: "memory")
#define SCHED0 __builtin_amdgcn_sched_barrier(0)
#define VMC(n) asm volatile("s_waitcnt vmcnt(" #n ")" ::: "memory")
#define MFMA16(AV, MB, BV)                                                            \
  __builtin_amdgcn_s_setprio(1);                                                      \
  _Pragma("unroll") for (int m_ = 0; m_ < 4; ++m_)                                    \
      _Pragma("unroll") for (int n_ = 0; n_ < 4; ++n_)                                \
          acc[(MB) + m_][n_] = __builtin_amdgcn_mfma_f32_16x16x32_bf16(               \
              AV[m_], BV[n_], acc[(MB) + m_][n_], 0, 0, 0);                           \
  __builtin_amdgcn_s_setprio(0)

  bf16x8 aL[4], aH[4];
  bf16x8 bU0[4], bU1[4], bV0[4], bV1[4];

  // ---- prologue: B(0)->bU; stage Ak0(0),Ak1(0),Ak0(1); drain all ----
  LOADB(bU0, bU1, 0);
  STG_A(0, 0);  // Ak0(0)
  STG_A(1, 0);  // Ak1(0)
  STG_A(0, 1);  // Ak0(1)
  VMC(0);
  BAR;

  for (int it = 0; it < NT / 2; ++it) {
    const int u = 2 * it, v = u + 1;
    const bool pf = (it < NT / 2 - 1);

    // ================= tile u (buf0, B-set bU) =================
    // -- P0: reads (0,kh0,mL); stage Ak1(u+1); load B(u+1)->bV --
    RD_A(aL, 0, 0, 0);
    STG_A(1, u + 1);
    LOADB(bV0, bV1, u + 1);
    BAR; LGKM0; SCHED0;
    MFMA16(aL, 0, bU0);
    BAR;

    // -- P1: reads (0,kh0,mH) --
    RD_A(aH, 0, 0, 64);
    BAR; LGKM0; SCHED0;
    MFMA16(aH, 4, bU0);
    BAR;

    // -- P2: reads (0,kh1,mL); stage Ak0(u+2) --
    RD_A(aL, 0, 1, 0);
    if (pf) STG_A(0, u + 2);
    BAR; LGKM0; SCHED0;
    MFMA16(aL, 0, bU1);
    BAR;

    // -- P3: reads (0,kh1,mH); drain (leave Ak0(u+2) in flight) --
    RD_A(aH, 0, 1, 64);
    BAR; LGKM0; SCHED0;
    MFMA16(aH, 4, bU1);
    if (pf) { VMC(2); } else { VMC(0); }  // it==31: u==62 -> drain all for v=63
    BAR;

    // ================= tile v (buf1, B-set bV) =================
    // -- P0: reads (1,kh0,mL); stage Ak1(v+1); load B(v+1)->bU --
    RD_A(aL, 1, 0, 0);
    if (pf) STG_A(1, v + 1);
    if (pf) LOADB(bU0, bU1, v + 1);
    BAR; LGKM0; SCHED0;
    MFMA16(aL, 0, bV0);
    BAR;

    // -- P1: reads (1,kh0,mH) --
    RD_A(aH, 1, 0, 64);
    BAR; LGKM0; SCHED0;
    MFMA16(aH, 4, bV0);
    BAR;

    // -- P2: reads (1,kh1,mL); stage Ak0(v+2) --
    RD_A(aL, 1, 1, 0);
    if (pf) STG_A(0, v + 2);
    BAR; LGKM0; SCHED0;
    MFMA16(aL, 0, bV1);
    BAR;

    // -- P3: reads (1,kh1,mH); drain --
    RD_A(aH, 1, 1, 64);
    BAR; LGKM0; SCHED0;
    MFMA16(aH, 4, bV1);
    if (pf) { VMC(2); }  // leaves Ak0(v+2); it==31: nothing outstanding
    BAR;
  }
#undef STG_A
#undef RD_A
#undef LOADB
#undef MFMA16
#undef BAR
#undef LGKM0
#undef SCHED0
#undef VMC

  // ---- epilogue: C/D layout col = lane&15, row = (lane>>4)*4 + j ----
#pragma unroll
  for (int n = 0; n < 4; ++n) {
    const int col = bcol + wn * 64 + n * 16 + fr;
    const float bb = bias[col];
#pragma unroll
    for (int m = 0; m < 8; ++m) {
      const int row0 = brow + wm * 128 + m * 16 + hi * 4;
#pragma unroll
      for (int j = 0; j < 4; ++j)
        C[(size_t)(row0 + j) * N_DIM + col] = acc[m][n][j] + bb;
    }
  }
}

// ---- fallback (only if ws too small): fp32 LDS-tiled GEMM ----
__global__ __launch_bounds__(256) void k_gemm_f32(
    const float* __restrict__ A, const float* __restrict__ W,
    const float* __restrict__ bias, float* __restrict__ C) {
  __shared__ float As[64][17];
  __shared__ float Ws[16][64];
  const int tid = threadIdx.x;
  const int tx = tid & 15, ty = tid >> 4;
  const int brow = blockIdx.y * 64, bcol = blockIdx.x * 64;
  float acc[4][4] = {};
  for (int ks = 0; ks < K_DIM; ks += 16) {
    {
      const int m = tid >> 2, k = (tid & 3) * 4;
      f32x4 v = *(const f32x4*)&A[(size_t)(brow + m) * K_DIM + ks + k];
      As[m][k] = v[0]; As[m][k + 1] = v[1]; As[m][k + 2] = v[2]; As[m][k + 3] = v[3];
    }
    {
      const int k = tid >> 4, n = (tid & 15) * 4;
      *(f32x4*)&Ws[k][n] = *(const f32x4*)&W[(size_t)(ks + k) * N_DIM + bcol + n];
    }
    __syncthreads();
#pragma unroll
    for (int k = 0; k < 16; ++k) {
      float av[4], bv[4];
#pragma unroll
      for (int i = 0; i < 4; ++i) av[i] = As[ty * 4 + i][k];
#pragma unroll
      for (int j = 0; j < 4; ++j) bv[j] = Ws[k][tx * 4 + j];
#pragma unroll
      for (int i = 0; i < 4; ++i)
#pragma unroll
        for (int j = 0; j < 4; ++j) acc[i][j] += av[i] * bv[j];
    }
    __syncthreads();
  }
#pragma unroll
  for (int i = 0; i < 4; ++i) {
    const int row = brow + ty * 4 + i;
#pragma unroll
    for (int j = 0; j < 4; ++j) {
      const int col = bcol + tx * 4 + j;
      C[(size_t)row * N_DIM + col] = acc[i][j] + bias[col];
    }
  }
}

extern "C" void kernel_launch(void* const* d_in, const int* in_sizes, int n_in,
                              void* d_out, int out_size, void* d_ws, size_t ws_size,
                              hipStream_t stream) {
  const float* inp = (const float*)d_in[0];   // [16384, 4096]
  const float* w = (const float*)d_in[1];     // [4096, 8192]
  const float* bias = (const float*)d_in[2];  // [8192]
  float* out = (float*)d_out;                 // [16384, 8192]

  const size_t needA = (size_t)M_DIM * K_DIM * sizeof(unsigned short);  // 128 MB
  const size_t needW = (size_t)N_DIM * K_DIM * sizeof(unsigned short);  // 64 MB

  if (ws_size >= needA + needW) {
    unsigned short* Abf = (unsigned short*)d_ws;
    unsigned short* Wtb = (unsigned short*)((char*)d_ws + needA);
    k_convert_a<<<2048, 256, 0, stream>>>(inp, Abf);
    k_convert_w_t<<<dim3(N_DIM / 64, K_DIM / 64), 256, 0, stream>>>(w, Wtb);
    k_gemm_8ph<<<(M_DIM / 256) * (N_DIM / 256), 512, 0, stream>>>(Abf, Wtb, bias, out);
  } else {
    k_gemm_f32<<<dim3(N_DIM / 64, M_DIM / 64), 256, 0, stream>>>(inp, w, bias, out);
  }
}

// Round 9
// 1453.774 us; speedup vs baseline: 12.4540x; 12.4540x over previous
//
#include <hip/hip_runtime.h>
#include <hip/hip_bf16.h>

#define M_DIM 16384
#define N_DIM 8192
#define K_DIM 4096
#define NT (K_DIM / 64)  // 64 K-tiles

typedef __attribute__((ext_vector_type(4))) float f32x4;
typedef __attribute__((ext_vector_type(8))) __bf16 bf16x8;
typedef __attribute__((ext_vector_type(4))) unsigned short u16x4;

static __device__ __forceinline__ unsigned short f2bf(float f) {
  __bf16 h = (__bf16)f;
  return __builtin_bit_cast(unsigned short, h);
}

static __device__ __forceinline__ void gl_lds16(const unsigned short* g, unsigned short* l) {
  __builtin_amdgcn_global_load_lds(
      (const __attribute__((address_space(1))) unsigned int*)g,
      (__attribute__((address_space(3))) unsigned int*)l, 16, 0, 0);
}

// ---- prep: A [M][K] f32 -> bf16 (same layout) ----
__global__ void k_convert_a(const float* __restrict__ a, unsigned short* __restrict__ o) {
  const size_t n8 = (size_t)M_DIM * K_DIM / 8;
  for (size_t i = (size_t)blockIdx.x * blockDim.x + threadIdx.x; i < n8;
       i += (size_t)gridDim.x * blockDim.x) {
    const f32x4* p = (const f32x4*)(a + i * 8);
    f32x4 v0 = p[0];
    f32x4 v1 = p[1];
    u16x4 r0, r1;
#pragma unroll
    for (int j = 0; j < 4; ++j) { r0[j] = f2bf(v0[j]); r1[j] = f2bf(v1[j]); }
    *(u16x4*)(o + i * 8) = r0;
    *(u16x4*)(o + i * 8 + 4) = r1;
  }
}

// ---- prep: W [K][N] f32 -> Wf in MFMA-FRAGMENT order ----
// Wf block (nt, kt): 512 elems at ((nt*128)+kt)*512; lane l (=hi*16+fr) holds
// 8 elems: col = nt*16 + (l&15), k = kt*32 + (l>>4)*8 + j. GEMM loads each
// block as ONE coalesced 1KB global_load_dwordx4 per wave, straight into the
// MFMA B operand (no LDS, no shuffle).
__global__ void k_convert_w_frag(const float* __restrict__ w, unsigned short* __restrict__ wf) {
  __shared__ float tile[64][65];
  const int bk = blockIdx.y * 64;  // k base
  const int bn = blockIdx.x * 64;  // col base
  const int t = threadIdx.x;       // 256
  const int c4 = (t & 15) * 4;
  const int r = t >> 4;
#pragma unroll
  for (int p = 0; p < 4; ++p) {
    const int row = r + p * 16;
    f32x4 v = *(const f32x4*)&w[(size_t)(bk + row) * N_DIM + bn + c4];
    tile[row][c4 + 0] = v[0];
    tile[row][c4 + 1] = v[1];
    tile[row][c4 + 2] = v[2];
    tile[row][c4 + 3] = v[3];
  }
  __syncthreads();
  const int fb = t >> 5;   // 0..7 -> (ntl, ktl)
  const int ntl = fb >> 1; // 0..3
  const int ktl = fb & 1;  // 0..1
  const int sub = t & 31;
  unsigned short* out = wf + ((size_t)(bn / 16 + ntl) * 128 + (bk / 32) + ktl) * 512;
#pragma unroll
  for (int q = 0; q < 2; ++q) {
    const int l = sub * 2 + q;  // lane 0..63
    const int col = ntl * 16 + (l & 15);
    const int k0 = ktl * 32 + (l >> 4) * 8;
    u16x4 o0, o1;
#pragma unroll
    for (int j = 0; j < 4; ++j) {
      o0[j] = f2bf(tile[k0 + j][col]);
      o1[j] = f2bf(tile[k0 + 4 + j][col]);
    }
    *(u16x4*)&out[l * 8] = o0;
    *(u16x4*)&out[l * 8 + 4] = o1;
  }
}

// ---- main GEMM: 256x256, BK=64; A in 96KB LDS (3 bufs), B global->reg ----
// Per tile: 2 phases {read 8 A-frags; [stage A(t+2), load B(t+1), drain];
// BAR; lgkm0; 16 MFMA; BAR}. B frags come from Wf as coalesced 1KB loads,
// double reg set bE/bO. vmcnt invariant at each P0 post-issue: outstanding
// {A(t+1):4, B(t):8, A(t+2):4, B(t+1):8} -> VMC(12) drains A(t+1)+B(t),
// both issued 2 phases (~650cy) earlier. 3 A-bufs: stage target (t+2)%3 was
// last read at t-1, republished by its end barrier -> WAR safe.
// A path (stage swizzle + read pattern) = round-3 verified, 0 conflicts.
__global__ __launch_bounds__(512) void k_gemm_bdir(
    const unsigned short* __restrict__ A, const unsigned short* __restrict__ Wf,
    const float* __restrict__ bias, float* __restrict__ C) {
  __shared__ __align__(16) unsigned short S[49152];  // 96 KB = 3 x 32KB A-tiles

  const int tid = threadIdx.x;
  const int lane = tid & 63;
  const int wave = tid >> 6;  // 0..7
  const int wm = wave >> 2;   // 0..1 -> 128-row half
  const int wn = wave & 3;    // 0..3 -> 64-col block
  const int fr = lane & 15;
  const int hi = lane >> 4;   // 0..3

  // T1: XCD-aware bijective swizzle (2048 blocks, %8==0)
  const int bid = blockIdx.x;
  const int swz = (bid & 7) * 256 + (bid >> 3);
  const int local = swz & 255;
  const int tm = local & 63;
  const int tn = (swz >> 8) * 4 + (local >> 6);
  const int brow = tm * 256;
  const int bcol = tn * 256;

  // A staging source (round-3 verbatim): row = tid>>3, swizzled k
  const int srow = tid >> 3;                             // 0..63
  const int skel = ((tid & 7) * 8) ^ ((srow & 7) << 3);  // swizzled k-elem
  const unsigned short* aS = A + (size_t)(brow + srow) * K_DIM + skel;

  // stage full A tile tt (256x64) into buf cb: regions h=0,1 (rows h*128..)
#define STG_A(tt, cb)                                                  \
  do {                                                                 \
    _Pragma("unroll") for (int h_ = 0; h_ < 2; ++h_) {                 \
      unsigned short* d_ = S + (cb)*16384 + h_ * 8192 + tid * 8;       \
      const unsigned short* g_ = aS + (size_t)(h_ * 128) * K_DIM + (size_t)(tt)*64; \
      gl_lds16(g_, d_);                                                \
      gl_lds16(g_ + (size_t)64 * K_DIM, d_ + 4096);                    \
    }                                                                  \
  } while (0)

  // A frag reads (round-3 verbatim): 0-conflict swizzle
  const int swk0 = (hi * 8) ^ ((fr & 7) << 3);
  const int swk1 = (32 + hi * 8) ^ ((fr & 7) << 3);
  const unsigned short* SAb = S + wm * 8192 + fr * 64;  // + c*16384 + mb + m*1024 + swk

#define RD_A(c, mb)                                                              \
  _Pragma("unroll") for (int m_ = 0; m_ < 4; ++m_) {                             \
    aK0[m_] = *(const bf16x8*)(SAb + (c)*16384 + (mb) + m_ * 1024 + swk0);       \
    aK1[m_] = *(const bf16x8*)(SAb + (c)*16384 + (mb) + m_ * 1024 + swk1);       \
  }

  // B fragment pointers: 4 n-blocks, each tile t = 1KB (kh0) + 1KB (kh1)
  const unsigned short* bP0 = Wf + (size_t)(bcol / 16 + wn * 4) * 65536 + (size_t)lane * 8;
#define LOADB(d0, d1, tt)                                                        \
  _Pragma("unroll") for (int n_ = 0; n_ < 4; ++n_) {                             \
    d0[n_] = *(const bf16x8*)(bP0 + (size_t)n_ * 65536 + (size_t)(tt)*1024);     \
    d1[n_] = *(const bf16x8*)(bP0 + (size_t)n_ * 65536 + (size_t)(tt)*1024 + 512); \
  }

  f32x4 acc[8][4] = {};

#define BAR __builtin_amdgcn_s_barrier()
#define LGKM0 asm volatile("s_waitcnt lgkmcnt(0)" ::: "memory")
#define SCHED0 __builtin_amdgcn_sched_barrier(0)
#define VMC(n) asm volatile("s_waitcnt vmcnt(" #n ")" ::: "memory")
#define MFMA16(MB, B0, B1)                                                            \
  __builtin_amdgcn_s_setprio(1);                                                      \
  _Pragma("unroll") for (int m_ = 0; m_ < 4; ++m_)                                    \
      _Pragma("unroll") for (int n_ = 0; n_ < 4; ++n_)                                \
          acc[(MB) + m_][n_] = __builtin_amdgcn_mfma_f32_16x16x32_bf16(               \
              aK0[m_], B0[n_], acc[(MB) + m_][n_], 0, 0, 0);                          \
  _Pragma("unroll") for (int m_ = 0; m_ < 4; ++m_)                                    \
      _Pragma("unroll") for (int n_ = 0; n_ < 4; ++n_)                                \
          acc[(MB) + m_][n_] = __builtin_amdgcn_mfma_f32_16x16x32_bf16(               \
              aK1[m_], B1[n_], acc[(MB) + m_][n_], 0, 0, 0);                          \
  __builtin_amdgcn_s_setprio(0)

  bf16x8 aK0[4], aK1[4];
  bf16x8 bE0[4], bE1[4], bO0[4], bO1[4];

  // ---- prologue: A(0)->buf0, A(1)->buf1, B(0)->bE; drain A(0) ----
  STG_A(0, 0);
  STG_A(1, 1);
  LOADB(bE0, bE1, 0);
  VMC(12);  // outstanding 16 -> drains A(0); leaves {A(1):4, B(0):8}
  BAR;

#define TILE(T, CUR0, CUR1, NXT0, NXT1)                              \
  do {                                                               \
    const int t_ = (T);                                              \
    const bool pfA = (t_ + 2 < NT), pfB = (t_ + 1 < NT);             \
    /* P0 */                                                         \
    RD_A(c0, 0);                                                     \
    if (pfA) STG_A(t_ + 2, c2);                                      \
    if (pfB) LOADB(NXT0, NXT1, t_ + 1);                              \
    if (pfA) { VMC(12); } else if (pfB) { VMC(8); } else { VMC(0); } \
    BAR; LGKM0; SCHED0;                                              \
    MFMA16(0, CUR0, CUR1);                                           \
    BAR;                                                             \
    /* P1 */                                                         \
    RD_A(c0, 4096);                                                  \
    BAR; LGKM0; SCHED0;                                              \
    MFMA16(4, CUR0, CUR1);                                           \
    BAR;                                                             \
  } while (0)

  int c0 = 0, c1 = 1, c2 = 2;
  for (int it = 0; it < NT / 2; ++it) {
    TILE(2 * it, bE0, bE1, bO0, bO1);
    { int tmp = c0; c0 = c1; c1 = c2; c2 = tmp; }
    TILE(2 * it + 1, bO0, bO1, bE0, bE1);
    { int tmp = c0; c0 = c1; c1 = c2; c2 = tmp; }
  }
#undef TILE
#undef STG_A
#undef RD_A
#undef LOADB
#undef MFMA16
#undef BAR
#undef LGKM0
#undef SCHED0
#undef VMC

  // ---- epilogue: C/D layout col = lane&15, row = (lane>>4)*4 + j ----
#pragma unroll
  for (int n = 0; n < 4; ++n) {
    const int col = bcol + wn * 64 + n * 16 + fr;
    const float bb = bias[col];
#pragma unroll
    for (int m = 0; m < 8; ++m) {
      const int row0 = brow + wm * 128 + m * 16 + hi * 4;
#pragma unroll
      for (int j = 0; j < 4; ++j)
        C[(size_t)(row0 + j) * N_DIM + col] = acc[m][n][j] + bb;
    }
  }
}

// ---- fallback (only if ws too small): fp32 LDS-tiled GEMM ----
__global__ __launch_bounds__(256) void k_gemm_f32(
    const float* __restrict__ A, const float* __restrict__ W,
    const float* __restrict__ bias, float* __restrict__ C) {
  __shared__ float As[64][17];
  __shared__ float Ws[16][64];
  const int tid = threadIdx.x;
  const int tx = tid & 15, ty = tid >> 4;
  const int brow = blockIdx.y * 64, bcol = blockIdx.x * 64;
  float acc[4][4] = {};
  for (int ks = 0; ks < K_DIM; ks += 16) {
    {
      const int m = tid >> 2, k = (tid & 3) * 4;
      f32x4 v = *(const f32x4*)&A[(size_t)(brow + m) * K_DIM + ks + k];
      As[m][k] = v[0]; As[m][k + 1] = v[1]; As[m][k + 2] = v[2]; As[m][k + 3] = v[3];
    }
    {
      const int k = tid >> 4, n = (tid & 15) * 4;
      *(f32x4*)&Ws[k][n] = *(const f32x4*)&W[(size_t)(ks + k) * N_DIM + bcol + n];
    }
    __syncthreads();
#pragma unroll
    for (int k = 0; k < 16; ++k) {
      float av[4], bv[4];
#pragma unroll
      for (int i = 0; i < 4; ++i) av[i] = As[ty * 4 + i][k];
#pragma unroll
      for (int j = 0; j < 4; ++j) bv[j] = Ws[k][tx * 4 + j];
#pragma unroll
      for (int i = 0; i < 4; ++i)
#pragma unroll
        for (int j = 0; j < 4; ++j) acc[i][j] += av[i] * bv[j];
    }
    __syncthreads();
  }
#pragma unroll
  for (int i = 0; i < 4; ++i) {
    const int row = brow + ty * 4 + i;
#pragma unroll
    for (int j = 0; j < 4; ++j) {
      const int col = bcol + tx * 4 + j;
      C[(size_t)row * N_DIM + col] = acc[i][j] + bias[col];
    }
  }
}

extern "C" void kernel_launch(void* const* d_in, const int* in_sizes, int n_in,
                              void* d_out, int out_size, void* d_ws, size_t ws_size,
                              hipStream_t stream) {
  const float* inp = (const float*)d_in[0];   // [16384, 4096]
  const float* w = (const float*)d_in[1];     // [4096, 8192]
  const float* bias = (const float*)d_in[2];  // [8192]
  float* out = (float*)d_out;                 // [16384, 8192]

  const size_t needA = (size_t)M_DIM * K_DIM * sizeof(unsigned short);  // 128 MB
  const size_t needW = (size_t)N_DIM * K_DIM * sizeof(unsigned short);  // 64 MB

  if (ws_size >= needA + needW) {
    unsigned short* Abf = (unsigned short*)d_ws;
    unsigned short* Wfr = (unsigned short*)((char*)d_ws + needA);
    k_convert_a<<<2048, 256, 0, stream>>>(inp, Abf);
    k_convert_w_frag<<<dim3(N_DIM / 64, K_DIM / 64), 256, 0, stream>>>(w, Wfr);
    k_gemm_bdir<<<(M_DIM / 256) * (N_DIM / 256), 512, 0, stream>>>(Abf, Wfr, bias, out);
  } else {
    k_gemm_f32<<<dim3(N_DIM / 64, M_DIM / 64), 256, 0, stream>>>(inp, w, bias, out);
  }
}

// Round 10
// 1311.747 us; speedup vs baseline: 13.8024x; 1.1083x over previous
//
#include <hip/hip_runtime.h>
#include <hip/hip_bf16.h>

#define M_DIM 16384
#define N_DIM 8192
#define K_DIM 4096
#define NT (K_DIM / 64)  // 64 K-tiles, 32 groups of 2

typedef __attribute__((ext_vector_type(4))) float f32x4;
typedef __attribute__((ext_vector_type(8))) __bf16 bf16x8;
typedef __attribute__((ext_vector_type(4))) unsigned short u16x4;

static __device__ __forceinline__ unsigned short f2bf(float f) {
  __bf16 h = (__bf16)f;
  return __builtin_bit_cast(unsigned short, h);
}

static __device__ __forceinline__ void gl_lds16(const unsigned short* g, unsigned short* l) {
  __builtin_amdgcn_global_load_lds(
      (const __attribute__((address_space(1))) unsigned int*)g,
      (__attribute__((address_space(3))) unsigned int*)l, 16, 0, 0);
}

// ---- prep: A [M][K] f32 -> bf16 (same layout) ----
__global__ void k_convert_a(const float* __restrict__ a, unsigned short* __restrict__ o) {
  const size_t n8 = (size_t)M_DIM * K_DIM / 8;
  for (size_t i = (size_t)blockIdx.x * blockDim.x + threadIdx.x; i < n8;
       i += (size_t)gridDim.x * blockDim.x) {
    const f32x4* p = (const f32x4*)(a + i * 8);
    f32x4 v0 = p[0];
    f32x4 v1 = p[1];
    u16x4 r0, r1;
#pragma unroll
    for (int j = 0; j < 4; ++j) { r0[j] = f2bf(v0[j]); r1[j] = f2bf(v1[j]); }
    *(u16x4*)(o + i * 8) = r0;
    *(u16x4*)(o + i * 8 + 4) = r1;
  }
}

// ---- prep: W [K][N] f32 -> Wt [N][K] bf16 (transpose + convert) ----
__global__ void k_convert_w_t(const float* __restrict__ w, unsigned short* __restrict__ wt) {
  __shared__ float tile[64][65];
  const int bk = blockIdx.y * 64;
  const int bn = blockIdx.x * 64;
  const int t = threadIdx.x;  // 256
  const int c4 = (t & 15) * 4;
  const int r = t >> 4;
#pragma unroll
  for (int p = 0; p < 4; ++p) {
    const int row = r + p * 16;
    f32x4 v = *(const f32x4*)&w[(size_t)(bk + row) * N_DIM + bn + c4];
    tile[row][c4 + 0] = v[0];
    tile[row][c4 + 1] = v[1];
    tile[row][c4 + 2] = v[2];
    tile[row][c4 + 3] = v[3];
  }
  __syncthreads();
#pragma unroll
  for (int p = 0; p < 4; ++p) {
    const int c = r + p * 16;
    u16x4 o;
#pragma unroll
    for (int j = 0; j < 4; ++j) o[j] = f2bf(tile[c4 + j][c]);
    *(u16x4*)&wt[(size_t)(bn + c) * K_DIM + bk + c4] = o;
  }
}

// ---- main GEMM: r5 skeleton, templated on wait style; M-half per dispatch ----
// PIN=1: BAR; lgkmcnt(0); sched_barrier(0); MFMA  (r5 exact)
// PIN=0: BAR; MFMA  -- compiler inserts its own fine-grained counted lgkmcnt
//        before each MFMA use (m97 asm evidence); race-safety: every phase's
//        reads' data was drained by the PREVIOUS phase's asm-clobbered VMC(8)
//        (ds/vmem ops cannot cross asm memory clobbers; only reg-only MFMAs
//        float, which is harmless).
// LDS 64KB-active = 2 tile-bufs x {Ak0,Ak1,Bk0,Bk1} x 16KB (256 rows x 32 k).
// Stage slots: ph0:Ak1(v) ph1:Bk1(v) ph2:Ak0(u+2) ph3:Bk0(u+2)
//              ph4:Ak1(u+2) ph5:Bk1(u+2) ph6:Ak0(v+2) ph7:Bk0(v+2)
// VMC(8) at end of every odd phase: drained stages are 4 phases old.
// Swizzle: phys granule = g ^ ((row>>1)&3) (r5-verified, 0 conflicts).
template <int PIN>
__global__ __launch_bounds__(512, 2) void k_gemm_8ph(
    const unsigned short* __restrict__ A, const unsigned short* __restrict__ Bt,
    const float* __restrict__ bias, float* __restrict__ C, int rowOff) {
  __shared__ __align__(16) unsigned short S[65536];  // 128 KB

  const int tid = threadIdx.x;
  const int lane = tid & 63;
  const int wave = tid >> 6;  // 0..7
  const int wm = wave >> 2;   // 0..1 -> 128-row half
  const int wn = wave & 3;    // 0..3 -> 64-col block
  const int fr = lane & 15;
  const int hi = lane >> 4;   // 0..3

  // T1: XCD-aware bijective swizzle for 1024 blocks (1024%8==0).
  // 32 row-tiles x 32 col-tiles per half-M dispatch.
  const int bid = blockIdx.x;
  const int swz = (bid & 7) * 128 + (bid >> 3);
  const int local = swz & 127;
  const int tm = local & 31;
  const int tn = (swz >> 7) * 4 + (local >> 5);
  const int brow = rowOff + tm * 256;
  const int bcol = tn * 256;

  // staging source: row = tid>>2 (+128 for 2nd gl_lds), dest granule tid&3,
  // source granule = dest ^ ((row>>1)&3) = dest ^ ((tid>>3)&3).
  const int srow2 = tid >> 2;
  const int sgel = ((tid & 3) ^ ((tid >> 3) & 3)) * 8;
  const unsigned short* aS = A + (size_t)(brow + srow2) * K_DIM + sgel;
  const unsigned short* bS = Bt + (size_t)(bcol + srow2) * K_DIM + sgel;

#define STG(reg, srcp, tt, kh)                                        \
  do {                                                                \
    unsigned short* d_ = S + ((tt)&1) * 32768 + (reg) + tid * 8;      \
    const unsigned short* g_ = (srcp) + (size_t)(tt)*64 + (kh)*32;    \
    gl_lds16(g_, d_);                                                 \
    gl_lds16(g_ + (size_t)128 * K_DIM, d_ + 4096);                    \
  } while (0)

  // frag-read swizzled granule: phys = hi ^ ((row>>1)&3); row bases mult of 16
  // so (row>>1)&3 == (fr>>1)&3 (lane-constant).
  const int swk = ((hi ^ ((fr >> 1) & 3)) * 8);
  const unsigned short* SA = S + (wm * 128 + fr) * 32 + swk;
  const unsigned short* SB = S + 16384 + (wn * 64 + fr) * 32 + swk;

#define RD_A(dst, X, h, mb)                                                       \
  _Pragma("unroll") for (int m_ = 0; m_ < 4; ++m_)                                \
      dst[m_] = *(const bf16x8*)(SA + (X)*32768 + (h)*8192 + ((mb) + m_ * 16) * 32);
#define RD_B(dst, X, h)                                                           \
  _Pragma("unroll") for (int n_ = 0; n_ < 4; ++n_)                                \
      dst[n_] = *(const bf16x8*)(SB + (X)*32768 + (h)*8192 + n_ * 512);

  f32x4 acc[8][4] = {};

#define BAR __builtin_amdgcn_s_barrier()
#define VMC(n) asm volatile("s_waitcnt vmcnt(" #n ")" ::: "memory")
#define WAITP                                                   \
  do {                                                          \
    if constexpr (PIN) {                                        \
      asm volatile("s_waitcnt lgkmcnt(0)" ::: "memory");        \
      __builtin_amdgcn_sched_barrier(0);                        \
    }                                                           \
  } while (0)
#define MFMA16(AV, MB, BV)                                                            \
  __builtin_amdgcn_s_setprio(1);                                                      \
  _Pragma("unroll") for (int m_ = 0; m_ < 4; ++m_)                                    \
      _Pragma("unroll") for (int n_ = 0; n_ < 4; ++n_)                                \
          acc[(MB) + m_][n_] = __builtin_amdgcn_mfma_f32_16x16x32_bf16(               \
              AV[m_], BV[n_], acc[(MB) + m_][n_], 0, 0, 0);                           \
  __builtin_amdgcn_s_setprio(0)

  // ---- prologue: tile0 all 4 regions + {Ak0,Bk0}(1); drain tile0 k0 pair ----
  STG(0, aS, 0, 0);      // Ak0(0)
  STG(16384, bS, 0, 0);  // Bk0(0)
  STG(8192, aS, 0, 1);   // Ak1(0)
  STG(24576, bS, 0, 1);  // Bk1(0)
  STG(0, aS, 1, 0);      // Ak0(1)
  STG(16384, bS, 1, 0);  // Bk0(1)
  VMC(8);                // drains Ak0(0),Bk0(0); leaves 4 stages (8 loads)
  BAR;

  const int NTH = NT / 2;
  for (int it = 0; it < NTH; ++it) {
    const int u = 2 * it, v = u + 1;
    const bool pf = (it < NTH - 1);
    bf16x8 aL[4], aH[4], bA[4], bB[4];

    // ---- ph0: u kk0 mL (8 reads); stage Ak1(v) ----
    RD_A(aL, 0, 0, 0); RD_B(bA, 0, 0);
    STG(8192, aS, v, 1);
    BAR; WAITP;
    MFMA16(aL, 0, bA);
    BAR;

    // ---- ph1: u kk0 mH (4 reads); stage Bk1(v); drain ----
    RD_A(aH, 0, 0, 64);
    STG(24576, bS, v, 1);
    BAR; WAITP;
    MFMA16(aH, 4, bA);
    VMC(8);  // drains Ak1(u),Bk1(u) (4 phases old)
    BAR;

    // ---- ph2: u kk1 mL (8 reads); stage Ak0(u+2) ----
    RD_A(aL, 0, 1, 0); RD_B(bB, 0, 1);
    if (pf) STG(0, aS, u + 2, 0);
    BAR; WAITP;
    MFMA16(aL, 0, bB);
    BAR;

    // ---- ph3: u kk1 mH (4 reads); stage Bk0(u+2); drain ----
    RD_A(aH, 0, 1, 64);
    if (pf) STG(16384, bS, u + 2, 0);
    BAR; WAITP;
    MFMA16(aH, 4, bB);
    if (pf) { VMC(8); } else { VMC(4); }  // drains Ak0(v),Bk0(v)
    BAR;

    // ---- ph4: v kk0 mL (8 reads); stage Ak1(u+2) ----
    RD_A(aL, 1, 0, 0); RD_B(bA, 1, 0);
    if (pf) STG(8192, aS, u + 2, 1);
    BAR; WAITP;
    MFMA16(aL, 0, bA);
    BAR;

    // ---- ph5: v kk0 mH (4 reads); stage Bk1(u+2); drain ----
    RD_A(aH, 1, 0, 64);
    if (pf) STG(24576, bS, u + 2, 1);
    BAR; WAITP;
    MFMA16(aH, 4, bA);
    if (pf) { VMC(8); } else { VMC(0); }  // drains Ak1(v),Bk1(v)
    BAR;

    // ---- ph6: v kk1 mL (8 reads); stage Ak0(v+2) ----
    RD_A(aL, 1, 1, 0); RD_B(bB, 1, 1);
    if (pf) STG(0, aS, v + 2, 0);
    BAR; WAITP;
    MFMA16(aL, 0, bB);
    BAR;

    // ---- ph7: v kk1 mH (4 reads); stage Bk0(v+2); drain ----
    RD_A(aH, 1, 1, 64);
    if (pf) STG(16384, bS, v + 2, 0);
    BAR; WAITP;
    MFMA16(aH, 4, bB);
    if (pf) { VMC(8); }  // drains Ak0(u+2),Bk0(u+2)
    BAR;
  }
#undef STG
#undef RD_A
#undef RD_B
#undef MFMA16
#undef BAR
#undef WAITP
#undef VMC

  // ---- epilogue: C/D layout col = lane&15, row = (lane>>4)*4 + j ----
#pragma unroll
  for (int n = 0; n < 4; ++n) {
    const int col = bcol + wn * 64 + n * 16 + fr;
    const float bb = bias[col];
#pragma unroll
    for (int m = 0; m < 8; ++m) {
      const int row0 = brow + wm * 128 + m * 16 + hi * 4;
#pragma unroll
      for (int j = 0; j < 4; ++j)
        C[(size_t)(row0 + j) * N_DIM + col] = acc[m][n][j] + bb;
    }
  }
}

// ---- fallback (only if ws too small): fp32 LDS-tiled GEMM ----
__global__ __launch_bounds__(256) void k_gemm_f32(
    const float* __restrict__ A, const float* __restrict__ W,
    const float* __restrict__ bias, float* __restrict__ C) {
  __shared__ float As[64][17];
  __shared__ float Ws[16][64];
  const int tid = threadIdx.x;
  const int tx = tid & 15, ty = tid >> 4;
  const int brow = blockIdx.y * 64, bcol = blockIdx.x * 64;
  float acc[4][4] = {};
  for (int ks = 0; ks < K_DIM; ks += 16) {
    {
      const int m = tid >> 2, k = (tid & 3) * 4;
      f32x4 v = *(const f32x4*)&A[(size_t)(brow + m) * K_DIM + ks + k];
      As[m][k] = v[0]; As[m][k + 1] = v[1]; As[m][k + 2] = v[2]; As[m][k + 3] = v[3];
    }
    {
      const int k = tid >> 4, n = (tid & 15) * 4;
      *(f32x4*)&Ws[k][n] = *(const f32x4*)&W[(size_t)(ks + k) * N_DIM + bcol + n];
    }
    __syncthreads();
#pragma unroll
    for (int k = 0; k < 16; ++k) {
      float av[4], bv[4];
#pragma unroll
      for (int i = 0; i < 4; ++i) av[i] = As[ty * 4 + i][k];
#pragma unroll
      for (int j = 0; j < 4; ++j) bv[j] = Ws[k][tx * 4 + j];
#pragma unroll
      for (int i = 0; i < 4; ++i)
#pragma unroll
        for (int j = 0; j < 4; ++j) acc[i][j] += av[i] * bv[j];
    }
    __syncthreads();
  }
#pragma unroll
  for (int i = 0; i < 4; ++i) {
    const int row = brow + ty * 4 + i;
#pragma unroll
    for (int j = 0; j < 4; ++j) {
      const int col = bcol + tx * 4 + j;
      C[(size_t)row * N_DIM + col] = acc[i][j] + bias[col];
    }
  }
}

extern "C" void kernel_launch(void* const* d_in, const int* in_sizes, int n_in,
                              void* d_out, int out_size, void* d_ws, size_t ws_size,
                              hipStream_t stream) {
  const float* inp = (const float*)d_in[0];   // [16384, 4096]
  const float* w = (const float*)d_in[1];     // [4096, 8192]
  const float* bias = (const float*)d_in[2];  // [8192]
  float* out = (float*)d_out;                 // [16384, 8192]

  const size_t needA = (size_t)M_DIM * K_DIM * sizeof(unsigned short);  // 128 MB
  const size_t needW = (size_t)N_DIM * K_DIM * sizeof(unsigned short);  // 64 MB

  if (ws_size >= needA + needW) {
    unsigned short* Abf = (unsigned short*)d_ws;
    unsigned short* Wtb = (unsigned short*)((char*)d_ws + needA);
    k_convert_a<<<2048, 256, 0, stream>>>(inp, Abf);
    k_convert_w_t<<<dim3(N_DIM / 64, K_DIM / 64), 256, 0, stream>>>(w, Wtb);
    const int halfGrid = (M_DIM / 2 / 256) * (N_DIM / 256);  // 1024
    // A/B: V1 = r5-exact pinned waits (rows 0..8191); V2 = compiler waits.
    k_gemm_8ph<1><<<halfGrid, 512, 0, stream>>>(Abf, Wtb, bias, out, 0);
    k_gemm_8ph<0><<<halfGrid, 512, 0, stream>>>(Abf, Wtb, bias, out, M_DIM / 2);
  } else {
    k_gemm_f32<<<dim3(N_DIM / 64, M_DIM / 64), 256, 0, stream>>>(inp, w, bias, out);
  }
}

// Round 11
// 1181.195 us; speedup vs baseline: 15.3279x; 1.1105x over previous
//
#include <hip/hip_runtime.h>
#include <hip/hip_bf16.h>

#define M_DIM 16384
#define N_DIM 8192
#define K_DIM 4096
#define NT (K_DIM / 64)  // 64 K-tiles, 32 groups of 2

typedef __attribute__((ext_vector_type(4))) float f32x4;
typedef __attribute__((ext_vector_type(8))) __bf16 bf16x8;
typedef __attribute__((ext_vector_type(4))) unsigned short u16x4;

static __device__ __forceinline__ unsigned short f2bf(float f) {
  __bf16 h = (__bf16)f;
  return __builtin_bit_cast(unsigned short, h);
}

static __device__ __forceinline__ void gl_lds16(const unsigned short* g, unsigned short* l) {
  __builtin_amdgcn_global_load_lds(
      (const __attribute__((address_space(1))) unsigned int*)g,
      (__attribute__((address_space(3))) unsigned int*)l, 16, 0, 0);
}

// ---- prep: A [M][K] f32 -> bf16 (same layout) ----
__global__ void k_convert_a(const float* __restrict__ a, unsigned short* __restrict__ o) {
  const size_t n8 = (size_t)M_DIM * K_DIM / 8;
  for (size_t i = (size_t)blockIdx.x * blockDim.x + threadIdx.x; i < n8;
       i += (size_t)gridDim.x * blockDim.x) {
    const f32x4* p = (const f32x4*)(a + i * 8);
    f32x4 v0 = p[0];
    f32x4 v1 = p[1];
    u16x4 r0, r1;
#pragma unroll
    for (int j = 0; j < 4; ++j) { r0[j] = f2bf(v0[j]); r1[j] = f2bf(v1[j]); }
    *(u16x4*)(o + i * 8) = r0;
    *(u16x4*)(o + i * 8 + 4) = r1;
  }
}

// ---- prep: W [K][N] f32 -> Wt [N][K] bf16 (transpose + convert) ----
__global__ void k_convert_w_t(const float* __restrict__ w, unsigned short* __restrict__ wt) {
  __shared__ float tile[64][65];
  const int bk = blockIdx.y * 64;
  const int bn = blockIdx.x * 64;
  const int t = threadIdx.x;  // 256
  const int c4 = (t & 15) * 4;
  const int r = t >> 4;
#pragma unroll
  for (int p = 0; p < 4; ++p) {
    const int row = r + p * 16;
    f32x4 v = *(const f32x4*)&w[(size_t)(bk + row) * N_DIM + bn + c4];
    tile[row][c4 + 0] = v[0];
    tile[row][c4 + 1] = v[1];
    tile[row][c4 + 2] = v[2];
    tile[row][c4 + 3] = v[3];
  }
  __syncthreads();
#pragma unroll
  for (int p = 0; p < 4; ++p) {
    const int c = r + p * 16;
    u16x4 o;
#pragma unroll
    for (int j = 0; j < 4; ++j) o[j] = f2bf(tile[c4 + j][c]);
    *(u16x4*)&wt[(size_t)(bn + c) * K_DIM + bk + c4] = o;
  }
}

// ---- main GEMM: 256x256, BK=64, TWO phases per K-tile (halved boundaries) ----
// LDS 128KB = 2 tile-bufs x {Ak0,Ak1,Bk0,Bk1} x 16KB (256 rows x 32 k).
// P0(tile): read A-mL (8 b128, both k-halves) + B-all (8 b128); 32 MFMA
//           (mL x 4n x 2kk). P1: read A-mH (8); 32 MFMA. B frags live across
//           both phases. 2 barriers/phase -> 4/tile (was 8).
// Stage slots (iter: u=2it buf0, v=u+1 buf1):
//   ph0(P0 u): A(v)->buf1      ph1(P1 u): B(u+2)->buf0, VMC(4)
//   ph2(P0 v): A(u+2)->buf0    ph3(P1 v): B(v+2)->buf1, VMC(4)
// Queue invariant entering ph0: [B(v)]=4. Drained loads are >=2 phases old.
// WAR: a region's reads are consumption-certified by its phase end-barrier
// >=1 barrier before its re-stage (A read P0+P1, restaged 1-2 phases later;
// B read P0 only, restaged next phase after end-barrier). FREE waits: MFMA
// consumes every read before the wave reaches the end-barrier, so passing
// the barrier implies all that wave's reads are serviced.
// Swizzle: phys granule = g ^ ((row>>1)&3) (r5-verified, 0 conflicts).
__global__ __launch_bounds__(512, 2) void k_gemm_2ph(
    const unsigned short* __restrict__ A, const unsigned short* __restrict__ Bt,
    const float* __restrict__ bias, float* __restrict__ C) {
  __shared__ __align__(16) unsigned short S[65536];  // 128 KB

  const int tid = threadIdx.x;
  const int lane = tid & 63;
  const int wave = tid >> 6;  // 0..7
  const int wm = wave >> 2;   // 0..1 -> 128-row half
  const int wn = wave & 3;    // 0..3 -> 64-col block
  const int fr = lane & 15;
  const int hi = lane >> 4;   // 0..3

  // T1: XCD-aware bijective swizzle (2048 blocks, %8==0)
  const int bid = blockIdx.x;
  const int swz = (bid & 7) * 256 + (bid >> 3);
  const int local = swz & 255;
  const int tm = local & 63;
  const int tn = (swz >> 8) * 4 + (local >> 6);
  const int brow = tm * 256;
  const int bcol = tn * 256;

  // staging source: row = tid>>2 (+128 for 2nd gl_lds), dest granule tid&3,
  // source granule = dest ^ ((row>>1)&3) = dest ^ ((tid>>3)&3).
  const int srow2 = tid >> 2;
  const int sgel = ((tid & 3) ^ ((tid >> 3) & 3)) * 8;
  const unsigned short* aS = A + (size_t)(brow + srow2) * K_DIM + sgel;
  const unsigned short* bS = Bt + (size_t)(bcol + srow2) * K_DIM + sgel;

#define STG(reg, srcp, tt, kh)                                        \
  do {                                                                \
    unsigned short* d_ = S + ((tt)&1) * 32768 + (reg) + tid * 8;      \
    const unsigned short* g_ = (srcp) + (size_t)(tt)*64 + (kh)*32;    \
    gl_lds16(g_, d_);                                                 \
    gl_lds16(g_ + (size_t)128 * K_DIM, d_ + 4096);                    \
  } while (0)

  // frag-read swizzled granule: phys = hi ^ ((row>>1)&3); row bases mult of 16
  // so (row>>1)&3 == (fr>>1)&3 (lane-constant).
  const int swk = ((hi ^ ((fr >> 1) & 3)) * 8);
  const unsigned short* SA = S + (wm * 128 + fr) * 32 + swk;
  const unsigned short* SB = S + 16384 + (wn * 64 + fr) * 32 + swk;

  bf16x8 av[8], bv[8];  // av[m*2+kk], bv[n*2+kk]

  // read A quad (rows mb..mb+63 of wave's half) both k-halves, buf X
#define RD_A8(mb, X)                                                              \
  _Pragma("unroll") for (int m_ = 0; m_ < 4; ++m_)                                \
      _Pragma("unroll") for (int h_ = 0; h_ < 2; ++h_)                            \
          av[m_ * 2 + h_] =                                                       \
              *(const bf16x8*)(SA + (X)*32768 + h_ * 8192 + ((mb) + m_ * 16) * 32);
#define RD_B8(X)                                                                  \
  _Pragma("unroll") for (int n_ = 0; n_ < 4; ++n_)                                \
      _Pragma("unroll") for (int h_ = 0; h_ < 2; ++h_)                            \
          bv[n_ * 2 + h_] = *(const bf16x8*)(SB + (X)*32768 + h_ * 8192 + n_ * 512);

  f32x4 acc[8][4] = {};

#define BAR __builtin_amdgcn_s_barrier()
#define VMC(n) asm volatile("s_waitcnt vmcnt(" #n ")" ::: "memory")
  // 32 MFMA: kk outer, then 4m x 4n (same-acc updates 16 insts apart)
#define MFMA32(MB)                                                                    \
  __builtin_amdgcn_s_setprio(1);                                                      \
  _Pragma("unroll") for (int k_ = 0; k_ < 2; ++k_)                                    \
      _Pragma("unroll") for (int m_ = 0; m_ < 4; ++m_)                                \
          _Pragma("unroll") for (int n_ = 0; n_ < 4; ++n_)                            \
              acc[(MB) + m_][n_] = __builtin_amdgcn_mfma_f32_16x16x32_bf16(           \
                  av[m_ * 2 + k_], bv[n_ * 2 + k_], acc[(MB) + m_][n_], 0, 0, 0);     \
  __builtin_amdgcn_s_setprio(0)

  // ---- prologue: A(0), B(0), B(1); drain A(0)+B(0), leave [B(1)]=4 ----
  STG(0, aS, 0, 0);      // Ak0(0)
  STG(8192, aS, 0, 1);   // Ak1(0)
  STG(16384, bS, 0, 0);  // Bk0(0)
  STG(24576, bS, 0, 1);  // Bk1(0)
  STG(16384, bS, 1, 0);  // Bk0(1)
  STG(24576, bS, 1, 1);  // Bk1(1)
  VMC(4);
  BAR;

  const int NTH = NT / 2;
  for (int it = 0; it < NTH; ++it) {
    const int u = 2 * it, v = u + 1;
    const bool pf = (it < NTH - 1);

    // ---- ph0: P0(u): A-mL + B (16 reads); stage A(v)->buf1 ----
    RD_A8(0, 0); RD_B8(0);
    STG(0, aS, v, 0); STG(8192, aS, v, 1);
    BAR;
    MFMA32(0);
    BAR;

    // ---- ph1: P1(u): A-mH (8 reads); stage B(u+2)->buf0; drain ----
    RD_A8(64, 0);
    if (pf) { STG(16384, bS, u + 2, 0); STG(24576, bS, u + 2, 1); }
    BAR;
    MFMA32(4);
    if (pf) { VMC(4); } else { VMC(0); }  // drains B(v),A(v); tail: drain all
    BAR;

    // ---- ph2: P0(v): A-mL + B (16 reads); stage A(u+2)->buf0 ----
    RD_A8(0, 1); RD_B8(1);
    if (pf) { STG(0, aS, u + 2, 0); STG(8192, aS, u + 2, 1); }
    BAR;
    MFMA32(0);
    BAR;

    // ---- ph3: P1(v): A-mH (8 reads); stage B(v+2)->buf1; drain ----
    RD_A8(64, 1);
    if (pf) { STG(16384, bS, v + 2, 0); STG(24576, bS, v + 2, 1); }
    BAR;
    MFMA32(4);
    if (pf) { VMC(4); }  // drains B(u+2),A(u+2); leaves [B(v+2)]
    BAR;
  }
#undef STG
#undef RD_A8
#undef RD_B8
#undef MFMA32
#undef BAR
#undef VMC

  // ---- epilogue: C/D layout col = lane&15, row = (lane>>4)*4 + j ----
#pragma unroll
  for (int n = 0; n < 4; ++n) {
    const int col = bcol + wn * 64 + n * 16 + fr;
    const float bb = bias[col];
#pragma unroll
    for (int m = 0; m < 8; ++m) {
      const int row0 = brow + wm * 128 + m * 16 + hi * 4;
#pragma unroll
      for (int j = 0; j < 4; ++j)
        C[(size_t)(row0 + j) * N_DIM + col] = acc[m][n][j] + bb;
    }
  }
}

// ---- fallback (only if ws too small): fp32 LDS-tiled GEMM ----
__global__ __launch_bounds__(256) void k_gemm_f32(
    const float* __restrict__ A, const float* __restrict__ W,
    const float* __restrict__ bias, float* __restrict__ C) {
  __shared__ float As[64][17];
  __shared__ float Ws[16][64];
  const int tid = threadIdx.x;
  const int tx = tid & 15, ty = tid >> 4;
  const int brow = blockIdx.y * 64, bcol = blockIdx.x * 64;
  float acc[4][4] = {};
  for (int ks = 0; ks < K_DIM; ks += 16) {
    {
      const int m = tid >> 2, k = (tid & 3) * 4;
      f32x4 v = *(const f32x4*)&A[(size_t)(brow + m) * K_DIM + ks + k];
      As[m][k] = v[0]; As[m][k + 1] = v[1]; As[m][k + 2] = v[2]; As[m][k + 3] = v[3];
    }
    {
      const int k = tid >> 4, n = (tid & 15) * 4;
      *(f32x4*)&Ws[k][n] = *(const f32x4*)&W[(size_t)(ks + k) * N_DIM + bcol + n];
    }
    __syncthreads();
#pragma unroll
    for (int k = 0; k < 16; ++k) {
      float av[4], bv[4];
#pragma unroll
      for (int i = 0; i < 4; ++i) av[i] = As[ty * 4 + i][k];
#pragma unroll
      for (int j = 0; j < 4; ++j) bv[j] = Ws[k][tx * 4 + j];
#pragma unroll
      for (int i = 0; i < 4; ++i)
#pragma unroll
        for (int j = 0; j < 4; ++j) acc[i][j] += av[i] * bv[j];
    }
    __syncthreads();
  }
#pragma unroll
  for (int i = 0; i < 4; ++i) {
    const int row = brow + ty * 4 + i;
#pragma unroll
    for (int j = 0; j < 4; ++j) {
      const int col = bcol + tx * 4 + j;
      C[(size_t)row * N_DIM + col] = acc[i][j] + bias[col];
    }
  }
}

extern "C" void kernel_launch(void* const* d_in, const int* in_sizes, int n_in,
                              void* d_out, int out_size, void* d_ws, size_t ws_size,
                              hipStream_t stream) {
  const float* inp = (const float*)d_in[0];   // [16384, 4096]
  const float* w = (const float*)d_in[1];     // [4096, 8192]
  const float* bias = (const float*)d_in[2];  // [8192]
  float* out = (float*)d_out;                 // [16384, 8192]

  const size_t needA = (size_t)M_DIM * K_DIM * sizeof(unsigned short);  // 128 MB
  const size_t needW = (size_t)N_DIM * K_DIM * sizeof(unsigned short);  // 64 MB

  if (ws_size >= needA + needW) {
    unsigned short* Abf = (unsigned short*)d_ws;
    unsigned short* Wtb = (unsigned short*)((char*)d_ws + needA);
    k_convert_a<<<2048, 256, 0, stream>>>(inp, Abf);
    k_convert_w_t<<<dim3(N_DIM / 64, K_DIM / 64), 256, 0, stream>>>(w, Wtb);
    k_gemm_2ph<<<(M_DIM / 256) * (N_DIM / 256), 512, 0, stream>>>(Abf, Wtb, bias, out);
  } else {
    k_gemm_f32<<<dim3(N_DIM / 64, M_DIM / 64), 256, 0, stream>>>(inp, w, bias, out);
  }
}